// Round 2
// baseline (92.805 us; speedup 1.0000x reference)
//
#include <hip/hip_runtime.h>
#include <hip/hip_bf16.h>

typedef unsigned short ushort_t;
typedef __attribute__((ext_vector_type(8))) short short8;
typedef __attribute__((ext_vector_type(4))) float f32x4;

__device__ __forceinline__ ushort_t f2bf(float f) {
    unsigned v;
    __builtin_memcpy(&v, &f, 4);
    unsigned r = (v + 0x7FFFu + ((v >> 16) & 1u)) >> 16;  // RNE
    return (ushort_t)r;
}

// Kernel 1 (fp32 inputs):
//  blocks 0..511  : s_proj[b][n][:] = slots[b,n,:] @ W_s + b_proj (all fp32),
//                   stored TRANSPOSED as sT[b][h][n] so k2 stages [h][n]-major.
//  blocks 512..543: pack W_f (rows 0..255 of W_proj) into bf16 MFMA B-frag order:
//                   Wpack[((kb*8+nt)*64+l)*8+i] = bf16(W_f[kb*32+(l>>4)*8+i][nt*16+(l&15)])
__global__ __launch_bounds__(128) void asd_k1(
        const float* __restrict__ slots,
        const float* __restrict__ Wproj,
        const float* __restrict__ bproj,
        float* __restrict__ sT,
        ushort_t* __restrict__ Wpack) {
    int bid = blockIdx.x;
    int tid = threadIdx.x;
    if (bid < 512) {
        __shared__ float sl[256];
        int b = bid >> 6, n = bid & 63;
        const float* srow = slots + (b * 64 + n) * 256;
        float2 v = ((const float2*)srow)[tid];           // 2 fp32 per thread
        sl[2 * tid]     = v.x;
        sl[2 * tid + 1] = v.y;
        __syncthreads();
        int h = tid;                                     // 128 threads = 128 h
        float acc = bproj[h];
        const float* Wcol = Wproj + 256 * 128 + h;       // W_s = W_proj[256:]
        #pragma unroll 8
        for (int d = 0; d < 256; ++d) {
            acc += sl[d] * Wcol[d * 128];
        }
        sT[(b * 128 + h) * 64 + n] = acc;
    } else {
        int gid = (bid - 512) * 128 + tid;               // 0..4095
        int l   = gid & 63;
        int idx = gid >> 6;                              // 0..63
        int kb  = idx >> 3, nt = idx & 7;
        int r0  = kb * 32 + ((l >> 4) << 3);
        int c   = nt * 16 + (l & 15);
        short8 frag;
        #pragma unroll
        for (int i = 0; i < 8; ++i)
            frag[i] = (short)f2bf(Wproj[(r0 + i) * 128 + c]);
        ((short8*)Wpack)[gid] = frag;
    }
}

// Kernel 2: one block per (b, 16-row t-tile). 256 threads = 4 waves.
// Phase B: MFMA 16x16x32 bf16 computes f_proj tile (16t x 128h) -> LDS fp32.
//          (feat fp32 -> bf16 converted at load; W_f pre-packed bf16.)
// Phase C: out[t,n] = sum_h relu(f[t,h]+s[n,h])*w[h] + b_head, fp32 VALU.
__global__ __launch_bounds__(256) void asd_k2(
        const float* __restrict__ feat,
        const float* __restrict__ sT,
        const ushort_t* __restrict__ Wpack,
        const float* __restrict__ whead,
        const float* __restrict__ bhead,
        float* __restrict__ out) {
    __shared__ float lds_s[128 * 68];    // s_proj [h][n], row stride 68 (pad)
    __shared__ float lds_f[16 * 132];    // f_proj [t][h], row stride 132 (pad)
    __shared__ float lds_w[128];

    int tid = threadIdx.x;
    int bid = blockIdx.x;
    int b   = bid >> 6;
    int t0  = (bid & 63) << 4;

    // ---- stage sT[b] (128h x 64n fp32) into LDS with padded rows ----
    const f32x4* src   = (const f32x4*)(sT + b * 128 * 64);
    f32x4*       ldsS4 = (f32x4*)lds_s;
    #pragma unroll
    for (int r = 0; r < 8; ++r) {
        int i4 = r * 256 + tid;          // 2048 float4s total
        int h  = i4 >> 4, c4 = i4 & 15;
        ldsS4[h * 17 + c4] = src[i4];
    }
    if (tid < 128) lds_w[tid] = whead[tid];
    float bh = bhead[0];

    // ---- phase B: f_proj tile via bf16 MFMA ----
    int l = tid & 63;
    int w = tid >> 6;
    int m = l & 15, q = l >> 4;
    int nt0 = 2 * w;                     // each wave owns 2 h-tiles of 16
    f32x4 acc0 = {0.f, 0.f, 0.f, 0.f};
    f32x4 acc1 = {0.f, 0.f, 0.f, 0.f};
    const short8* Wp = (const short8*)Wpack;
    #pragma unroll
    for (int kb = 0; kb < 8; ++kb) {
        const float* arow = feat + (b * 1024 + t0 + m) * 256 + kb * 32 + q * 8;
        f32x4 af0 = *(const f32x4*)arow;
        f32x4 af1 = *(const f32x4*)(arow + 4);
        short8 A;
        #pragma unroll
        for (int i = 0; i < 4; ++i) {
            A[i]     = (short)f2bf(af0[i]);
            A[4 + i] = (short)f2bf(af1[i]);
        }
        short8 B0 = Wp[(kb * 8 + nt0) * 64 + l];
        short8 B1 = Wp[(kb * 8 + nt0 + 1) * 64 + l];
        acc0 = __builtin_amdgcn_mfma_f32_16x16x32_bf16(A, B0, acc0, 0, 0, 0);
        acc1 = __builtin_amdgcn_mfma_f32_16x16x32_bf16(A, B1, acc1, 0, 0, 0);
    }
    #pragma unroll
    for (int r = 0; r < 4; ++r) {
        int row = q * 4 + r;             // C/D layout: col=lane&15, row=(lane>>4)*4+reg
        lds_f[row * 132 + nt0 * 16 + m]       = acc0[r];
        lds_f[row * 132 + (nt0 + 1) * 16 + m] = acc1[r];
    }
    __syncthreads();

    // ---- phase C: relu-reduce over h ----
    int t = tid >> 4, ng = tid & 15;     // thread owns (t, n = 4*ng..4*ng+3)
    const f32x4* fR = (const f32x4*)(lds_f + t * 132);
    float a0 = bh, a1 = bh, a2 = bh, a3 = bh;
    #pragma unroll 8
    for (int h4 = 0; h4 < 32; ++h4) {
        f32x4 f4 = fR[h4];
        #pragma unroll
        for (int i = 0; i < 4; ++i) {
            int h = h4 * 4 + i;
            f32x4 s4 = ldsS4[h * 17 + ng];
            float wv = lds_w[h];
            float x0 = fmaxf(f4[i] + s4[0], 0.f);
            float x1 = fmaxf(f4[i] + s4[1], 0.f);
            float x2 = fmaxf(f4[i] + s4[2], 0.f);
            float x3 = fmaxf(f4[i] + s4[3], 0.f);
            a0 += x0 * wv;
            a1 += x1 * wv;
            a2 += x2 * wv;
            a3 += x3 * wv;
        }
    }
    f32x4 o = {a0, a1, a2, a3};
    *(f32x4*)(out + (b * 1024 + t0 + t) * 64 + 4 * ng) = o;
}

extern "C" void kernel_launch(void* const* d_in, const int* in_sizes, int n_in,
                              void* d_out, int out_size, void* d_ws, size_t ws_size,
                              hipStream_t stream) {
    const float* feat  = (const float*)d_in[0];  // (8,1024,256) fp32
    const float* slots = (const float*)d_in[1];  // (8,64,256)   fp32
    const float* Wproj = (const float*)d_in[2];  // (512,128)    fp32
    const float* bproj = (const float*)d_in[3];  // (128,)       fp32
    const float* whead = (const float*)d_in[4];  // (128,)       fp32
    const float* bhead = (const float*)d_in[5];  // (1,)         fp32
    float* out = (float*)d_out;                  // (8,1024,64)  fp32

    float*    sT    = (float*)d_ws;                         // 8*128*64*4 = 256 KB
    ushort_t* Wpack = (ushort_t*)((char*)d_ws + 262144);    // 64 KB

    hipLaunchKernelGGL(asd_k1, dim3(544), dim3(128), 0, stream,
                       slots, Wproj, bproj, sT, Wpack);
    hipLaunchKernelGGL(asd_k2, dim3(512), dim3(256), 0, stream,
                       feat, sT, Wpack, whead, bhead, out);
}

// Round 3
// 82.089 us; speedup vs baseline: 1.1305x; 1.1305x over previous
//
#include <hip/hip_runtime.h>
#include <hip/hip_bf16.h>
#include <hip/hip_fp16.h>

typedef unsigned short ushort_t;
typedef unsigned int uint_t;
typedef __attribute__((ext_vector_type(8))) short short8;
typedef __attribute__((ext_vector_type(4))) float f32x4;
typedef __attribute__((ext_vector_type(4))) unsigned int uint4v;
typedef __attribute__((ext_vector_type(2))) _Float16 half2v;

#if defined(__has_builtin)
#if __has_builtin(__builtin_amdgcn_fdot2)
#define HAVE_FDOT2 1
#endif
#endif

__device__ __forceinline__ ushort_t f2bf(float f) {
    unsigned v;
    __builtin_memcpy(&v, &f, 4);
    unsigned r = (v + 0x7FFFu + ((v >> 16) & 1u)) >> 16;  // RNE
    return (ushort_t)r;
}

// Kernel 1 (512 threads/block):
//  blocks 0..255  : s_proj for (b, 2 slots). Threads = 2n x 128h x 2 d-halves
//                   (d-split gives 2 waves/SIMD for latency hiding; LDS combine).
//                   Output written as f16 in k2's staging layout:
//                   s2[b*8192 + (h>>1)*128 + n*2 + (h&1)]  (i.e. [b][h2][n] half2)
//  blocks 256..263: pack W_f (rows 0..255 of W_proj) into bf16 MFMA B-frag order.
__global__ __launch_bounds__(512) void asd_k1(
        const float* __restrict__ slots,
        const float* __restrict__ Wproj,
        const float* __restrict__ bproj,
        ushort_t* __restrict__ s2,
        ushort_t* __restrict__ Wpack) {
    int bid = blockIdx.x;
    int tid = threadIdx.x;
    if (bid < 256) {
        __shared__ float sl[512];     // 2 slot rows x 256 d
        __shared__ float part[256];   // partial sums from d-half 1
        int b  = bid >> 5;
        int n0 = (bid & 31) * 2;
        sl[tid] = slots[(b * 64 + n0) * 256 + tid];   // rows n0,n0+1 contiguous
        __syncthreads();
        int dh = tid >> 8;            // d-half 0/1
        int hn = tid & 255;
        int nl = hn >> 7;             // local n 0/1
        int h  = hn & 127;
        const float* Wcol = Wproj + 256 * 128 + dh * 128 * 128 + h;  // W_s = W_proj[256:]
        const float* srow = sl + nl * 256 + dh * 128;
        float acc = 0.f;
        #pragma unroll 8
        for (int d = 0; d < 128; ++d)
            acc += srow[d] * Wcol[d * 128];
        if (dh) part[hn] = acc;
        __syncthreads();
        if (!dh) {
            float v = acc + part[hn] + bproj[h];
            _Float16 hv = (_Float16)v;
            ushort_t u;
            __builtin_memcpy(&u, &hv, 2);
            int n = n0 + nl;
            s2[b * 8192 + (h >> 1) * 128 + n * 2 + (h & 1)] = u;
        }
    } else {
        int gid = (bid - 256) * 512 + tid;   // 0..4095
        int l   = gid & 63;
        int idx = gid >> 6;                  // 0..63
        int kb  = idx >> 3, nt = idx & 7;
        int r0  = kb * 32 + ((l >> 4) << 3);
        int c   = nt * 16 + (l & 15);
        short8 frag;
        #pragma unroll
        for (int i = 0; i < 8; ++i)
            frag[i] = (short)f2bf(Wproj[(r0 + i) * 128 + c]);
        ((short8*)Wpack)[gid] = frag;
    }
}

// Kernel 2: one block per (b, 16-row t-tile). 256 threads = 4 waves.
// Phase B: MFMA 16x16x32 bf16 computes f_proj tile (16t x 128h) -> LDS f16.
// Phase C: out[t,n] = sum_h relu(f+s)*w + b_head via pk_f16 add/max + v_dot2_f32_f16.
__global__ __launch_bounds__(256) void asd_k2(
        const float* __restrict__ feat,
        const ushort_t* __restrict__ s2g,
        const ushort_t* __restrict__ Wpack,
        const float* __restrict__ whead,
        const float* __restrict__ bhead,
        float* __restrict__ out) {
    __shared__ uint_t   s2_lds[64 * 68];   // [h2][n] half2-as-uint, row stride 68
    __shared__ ushort_t f_lds[16 * 132];   // [t][h] f16, row stride 132 (264 B)
    __shared__ uint_t   w2_lds[64];        // w_head as half2

    int tid = threadIdx.x;
    int bid = blockIdx.x;
    int b   = bid >> 6;
    int t0  = (bid & 63) << 4;

    // ---- stage s2[b] (64 h2 x 64 n half2 = 16 KB) into LDS, padded rows ----
    const uint4v* src = (const uint4v*)(s2g + b * 8192);
    #pragma unroll
    for (int r = 0; r < 4; ++r) {
        int i4 = r * 256 + tid;            // 1024 16B chunks
        int h2 = i4 >> 4, c = i4 & 15;
        *(uint4v*)(s2_lds + h2 * 68 + c * 4) = src[i4];
    }
    if (tid < 64) {
        half2v w2 = { (_Float16)whead[2 * tid], (_Float16)whead[2 * tid + 1] };
        uint_t u;
        __builtin_memcpy(&u, &w2, 4);
        w2_lds[tid] = u;
    }
    float bh = bhead[0];

    // ---- phase B: f_proj tile via bf16 MFMA ----
    int l = tid & 63;
    int w = tid >> 6;
    int m = l & 15, q = l >> 4;
    int nt0 = 2 * w;                       // each wave owns 2 h-tiles of 16
    f32x4 acc0 = {0.f, 0.f, 0.f, 0.f};
    f32x4 acc1 = {0.f, 0.f, 0.f, 0.f};
    const short8* Wp = (const short8*)Wpack;
    #pragma unroll
    for (int kb = 0; kb < 8; ++kb) {
        const float* arow = feat + (b * 1024 + t0 + m) * 256 + kb * 32 + q * 8;
        f32x4 af0 = *(const f32x4*)arow;
        f32x4 af1 = *(const f32x4*)(arow + 4);
        short8 A;
        #pragma unroll
        for (int i = 0; i < 4; ++i) {
            A[i]     = (short)f2bf(af0[i]);
            A[4 + i] = (short)f2bf(af1[i]);
        }
        short8 B0 = Wp[(kb * 8 + nt0) * 64 + l];
        short8 B1 = Wp[(kb * 8 + nt0 + 1) * 64 + l];
        acc0 = __builtin_amdgcn_mfma_f32_16x16x32_bf16(A, B0, acc0, 0, 0, 0);
        acc1 = __builtin_amdgcn_mfma_f32_16x16x32_bf16(A, B1, acc1, 0, 0, 0);
    }
    #pragma unroll
    for (int r = 0; r < 4; ++r) {
        int row = q * 4 + r;               // C/D: col=lane&15 -> h, row -> t
        _Float16 v0 = (_Float16)acc0[r];
        _Float16 v1 = (_Float16)acc1[r];
        ushort_t u0, u1;
        __builtin_memcpy(&u0, &v0, 2);
        __builtin_memcpy(&u1, &v1, 2);
        f_lds[row * 132 + nt0 * 16 + m]       = u0;
        f_lds[row * 132 + (nt0 + 1) * 16 + m] = u1;
    }
    __syncthreads();

    // ---- phase C: relu-reduce over h (f16 packed + dot2, fp32 acc) ----
    int t = tid >> 4, ng = tid & 15;       // thread owns (t, n = 4*ng..4*ng+3)
    const ushort_t* fR = f_lds + t * 132;
    float a0 = bh, a1 = bh, a2 = bh, a3 = bh;
    const half2v hz = { (_Float16)0.f, (_Float16)0.f };
    #pragma unroll 8
    for (int h2 = 0; h2 < 64; ++h2) {
        uint_t fu = *(const uint_t*)(fR + 2 * h2);
        half2v f2;
        __builtin_memcpy(&f2, &fu, 4);
        uint4v s4 = *(const uint4v*)(s2_lds + h2 * 68 + 4 * ng);
        uint_t wu = w2_lds[h2];
        half2v w2;
        __builtin_memcpy(&w2, &wu, 4);
        float* accs[4] = {&a0, &a1, &a2, &a3};
        #pragma unroll
        for (int j = 0; j < 4; ++j) {
            uint_t su = s4[j];
            half2v sv;
            __builtin_memcpy(&sv, &su, 4);
            half2v x = f2 + sv;
            x = __builtin_elementwise_max(x, hz);
#ifdef HAVE_FDOT2
            *accs[j] = __builtin_amdgcn_fdot2(x, w2, *accs[j], false);
#else
            *accs[j] += (float)x[0] * (float)w2[0] + (float)x[1] * (float)w2[1];
#endif
        }
    }
    f32x4 o = {a0, a1, a2, a3};
    *(f32x4*)(out + (b * 1024 + t0 + t) * 64 + 4 * ng) = o;
}

extern "C" void kernel_launch(void* const* d_in, const int* in_sizes, int n_in,
                              void* d_out, int out_size, void* d_ws, size_t ws_size,
                              hipStream_t stream) {
    const float* feat  = (const float*)d_in[0];  // (8,1024,256) fp32
    const float* slots = (const float*)d_in[1];  // (8,64,256)   fp32
    const float* Wproj = (const float*)d_in[2];  // (512,128)    fp32
    const float* bproj = (const float*)d_in[3];  // (128,)       fp32
    const float* whead = (const float*)d_in[4];  // (128,)       fp32
    const float* bhead = (const float*)d_in[5];  // (1,)         fp32
    float* out = (float*)d_out;                  // (8,1024,64)  fp32

    ushort_t* s2    = (ushort_t*)d_ws;                      // 8*64*128*2 = 128 KB
    ushort_t* Wpack = (ushort_t*)((char*)d_ws + 131072);    // 64 KB

    hipLaunchKernelGGL(asd_k1, dim3(264), dim3(512), 0, stream,
                       slots, Wproj, bproj, s2, Wpack);
    hipLaunchKernelGGL(asd_k2, dim3(512), dim3(256), 0, stream,
                       feat, s2, Wpack, whead, bhead, out);
}

// Round 4
// 79.223 us; speedup vs baseline: 1.1714x; 1.0362x over previous
//
#include <hip/hip_runtime.h>
#include <hip/hip_bf16.h>
#include <hip/hip_fp16.h>

typedef unsigned short ushort_t;
typedef unsigned int uint_t;
typedef __attribute__((ext_vector_type(8))) short short8;
typedef __attribute__((ext_vector_type(4))) float f32x4;
typedef __attribute__((ext_vector_type(4))) unsigned int uint4v;
typedef __attribute__((ext_vector_type(2))) _Float16 half2v;

#if defined(__has_builtin)
#if __has_builtin(__builtin_amdgcn_fdot2)
#define HAVE_FDOT2 1
#endif
#endif

__device__ __forceinline__ ushort_t f2bf(float f) {
    unsigned v;
    __builtin_memcpy(&v, &f, 4);
    unsigned r = (v + 0x7FFFu + ((v >> 16) & 1u)) >> 16;  // RNE
    return (ushort_t)r;
}

// Kernel 1 (1024 threads/block):
//  blocks 0..255  : s_proj for (b, 2 slots). Threads = 4 d-quarters x 2n x 128h
//                   (4-way d-split -> 64-iter chains, 16 waves/CU; LDS tree-combine).
//                   Output f16 in k2's staging layout:
//                   s2[b*8192 + (h>>1)*128 + n*2 + (h&1)]   ([b][h2][n] half2)
//  blocks 256..259: pack W_f (rows 0..255 of W_proj) into bf16 MFMA B-frag order:
//                   Wpack[((kb*8+nt)*64+l)*8+i] = bf16(W_f[kb*32+(l>>4)*8+i][nt*16+(l&15)])
__global__ __launch_bounds__(1024) void asd_k1(
        const float* __restrict__ slots,
        const float* __restrict__ Wproj,
        const float* __restrict__ bproj,
        ushort_t* __restrict__ s2,
        ushort_t* __restrict__ Wpack) {
    int bid = blockIdx.x;
    int tid = threadIdx.x;
    if (bid < 256) {
        __shared__ float sl[512];        // 2 slot rows x 256 d
        __shared__ float part[3][256];   // partials from d-quarters 1..3
        int b  = bid >> 5;
        int n0 = (bid & 31) * 2;
        const float* srow = slots + (b * 64 + n0) * 256;
        if (tid < 256) {
            float2 v = ((const float2*)srow)[tid];
            sl[2 * tid]     = v.x;
            sl[2 * tid + 1] = v.y;
        }
        __syncthreads();
        int dh = tid >> 8;               // d-quarter 0..3
        int nl = (tid >> 7) & 1;         // local n 0/1
        int h  = tid & 127;
        const float* Wcol = Wproj + 256 * 128 + dh * 64 * 128 + h;  // W_s = W_proj[256:]
        const float* sr   = sl + nl * 256 + dh * 64;
        float acc = 0.f;
        #pragma unroll 8
        for (int d = 0; d < 64; ++d)
            acc += sr[d] * Wcol[d * 128];
        if (dh) part[dh - 1][nl * 128 + h] = acc;
        __syncthreads();
        if (dh == 0) {
            float v = acc + part[0][nl * 128 + h] + part[1][nl * 128 + h]
                          + part[2][nl * 128 + h] + bproj[h];
            _Float16 hv = (_Float16)v;
            ushort_t u;
            __builtin_memcpy(&u, &hv, 2);
            int n = n0 + nl;
            s2[b * 8192 + (h >> 1) * 128 + n * 2 + (h & 1)] = u;
        }
    } else {
        int gid = (bid - 256) * 1024 + tid;  // 0..4095
        int l   = gid & 63;
        int idx = gid >> 6;                  // 0..63
        int kb  = idx >> 3, nt = idx & 7;
        int r0  = kb * 32 + ((l >> 4) << 3);
        int c   = nt * 16 + (l & 15);
        short8 frag;
        #pragma unroll
        for (int i = 0; i < 8; ++i)
            frag[i] = (short)f2bf(Wproj[(r0 + i) * 128 + c]);
        ((short8*)Wpack)[gid] = frag;
    }
}

// Kernel 2: one block per (b, 16-row t-tile). 256 threads = 4 waves.
// Phase B: MFMA 16x16x32 bf16 computes f_proj tile (16t x 128h) -> LDS f16.
//          feat fp32 -> bf16 via v_cvt_pk_bf16_f32 (__float22bfloat162_rn).
// Phase C: out[t,n] = sum_h relu(f+s)*w + b_head via pk_f16 add/max + v_dot2_f32_f16.
__global__ __launch_bounds__(256) void asd_k2(
        const float* __restrict__ feat,
        const ushort_t* __restrict__ s2g,
        const ushort_t* __restrict__ Wpack,
        const float* __restrict__ whead,
        const float* __restrict__ bhead,
        float* __restrict__ out) {
    __shared__ uint_t   s2_lds[64 * 68];   // [h2][n] half2-as-uint, row stride 68
    __shared__ ushort_t f_lds[16 * 132];   // [t][h] f16, row stride 132 (264 B)
    __shared__ uint_t   w2_lds[64];        // w_head as half2

    int tid = threadIdx.x;
    int bid = blockIdx.x;
    int b   = bid >> 6;
    int t0  = (bid & 63) << 4;

    if (tid < 64) {
        half2v w2 = { (_Float16)whead[2 * tid], (_Float16)whead[2 * tid + 1] };
        uint_t u;
        __builtin_memcpy(&u, &w2, 4);
        w2_lds[tid] = u;
    }
    // ---- stage s2[b] (64 h2 x 64 n half2 = 16 KB) into LDS, padded rows ----
    const uint4v* src = (const uint4v*)(s2g + b * 8192);
    #pragma unroll
    for (int r = 0; r < 4; ++r) {
        int i4 = r * 256 + tid;            // 1024 16B chunks
        int h2 = i4 >> 4, c = i4 & 15;
        *(uint4v*)(s2_lds + h2 * 68 + c * 4) = src[i4];
    }
    float bh = bhead[0];

    // ---- phase B: f_proj tile via bf16 MFMA ----
    int l = tid & 63;
    int w = tid >> 6;
    int m = l & 15, q = l >> 4;
    int nt0 = 2 * w;                       // each wave owns 2 h-tiles of 16
    f32x4 acc0 = {0.f, 0.f, 0.f, 0.f};
    f32x4 acc1 = {0.f, 0.f, 0.f, 0.f};
    const short8* Wp = (const short8*)Wpack;
    #pragma unroll
    for (int kb = 0; kb < 8; ++kb) {
        const float* arow = feat + (b * 1024 + t0 + m) * 256 + kb * 32 + q * 8;
        f32x4 af0 = *(const f32x4*)arow;
        f32x4 af1 = *(const f32x4*)(arow + 4);
        __hip_bfloat162 c0 = __float22bfloat162_rn(make_float2(af0[0], af0[1]));
        __hip_bfloat162 c1 = __float22bfloat162_rn(make_float2(af0[2], af0[3]));
        __hip_bfloat162 c2 = __float22bfloat162_rn(make_float2(af1[0], af1[1]));
        __hip_bfloat162 c3 = __float22bfloat162_rn(make_float2(af1[2], af1[3]));
        uint_t u0, u1, u2, u3;
        __builtin_memcpy(&u0, &c0, 4);
        __builtin_memcpy(&u1, &c1, 4);
        __builtin_memcpy(&u2, &c2, 4);
        __builtin_memcpy(&u3, &c3, 4);
        uint4v au = {u0, u1, u2, u3};
        short8 A;
        __builtin_memcpy(&A, &au, 16);
        short8 B0 = Wp[(kb * 8 + nt0) * 64 + l];
        short8 B1 = Wp[(kb * 8 + nt0 + 1) * 64 + l];
        acc0 = __builtin_amdgcn_mfma_f32_16x16x32_bf16(A, B0, acc0, 0, 0, 0);
        acc1 = __builtin_amdgcn_mfma_f32_16x16x32_bf16(A, B1, acc1, 0, 0, 0);
    }
    #pragma unroll
    for (int r = 0; r < 4; ++r) {
        int row = q * 4 + r;               // C/D: col=lane&15 -> h, row -> t
        _Float16 v0 = (_Float16)acc0[r];
        _Float16 v1 = (_Float16)acc1[r];
        ushort_t u0, u1;
        __builtin_memcpy(&u0, &v0, 2);
        __builtin_memcpy(&u1, &v1, 2);
        f_lds[row * 132 + nt0 * 16 + m]       = u0;
        f_lds[row * 132 + (nt0 + 1) * 16 + m] = u1;
    }
    __syncthreads();

    // ---- phase C: relu-reduce over h (f16 packed + dot2, fp32 acc) ----
    int t = tid >> 4, ng = tid & 15;       // thread owns (t, n = 4*ng..4*ng+3)
    const ushort_t* fR = f_lds + t * 132;
    float a0 = bh, a1 = bh, a2 = bh, a3 = bh;
    const half2v hz = { (_Float16)0.f, (_Float16)0.f };
    #pragma unroll 8
    for (int h2 = 0; h2 < 64; ++h2) {
        uint_t fu = *(const uint_t*)(fR + 2 * h2);
        half2v f2;
        __builtin_memcpy(&f2, &fu, 4);
        uint4v s4 = *(const uint4v*)(s2_lds + h2 * 68 + 4 * ng);
        uint_t wu = w2_lds[h2];
        half2v w2;
        __builtin_memcpy(&w2, &wu, 4);
        float* accs[4] = {&a0, &a1, &a2, &a3};
        #pragma unroll
        for (int j = 0; j < 4; ++j) {
            uint_t su = s4[j];
            half2v sv;
            __builtin_memcpy(&sv, &su, 4);
            half2v x = f2 + sv;
            x = __builtin_elementwise_max(x, hz);
#ifdef HAVE_FDOT2
            *accs[j] = __builtin_amdgcn_fdot2(x, w2, *accs[j], false);
#else
            *accs[j] += (float)x[0] * (float)w2[0] + (float)x[1] * (float)w2[1];
#endif
        }
    }
    f32x4 o = {a0, a1, a2, a3};
    *(f32x4*)(out + (b * 1024 + t0 + t) * 64 + 4 * ng) = o;
}

extern "C" void kernel_launch(void* const* d_in, const int* in_sizes, int n_in,
                              void* d_out, int out_size, void* d_ws, size_t ws_size,
                              hipStream_t stream) {
    const float* feat  = (const float*)d_in[0];  // (8,1024,256) fp32
    const float* slots = (const float*)d_in[1];  // (8,64,256)   fp32
    const float* Wproj = (const float*)d_in[2];  // (512,128)    fp32
    const float* bproj = (const float*)d_in[3];  // (128,)       fp32
    const float* whead = (const float*)d_in[4];  // (128,)       fp32
    const float* bhead = (const float*)d_in[5];  // (1,)         fp32
    float* out = (float*)d_out;                  // (8,1024,64)  fp32

    ushort_t* s2    = (ushort_t*)d_ws;                      // 8*64*128*2 = 128 KB
    ushort_t* Wpack = (ushort_t*)((char*)d_ws + 131072);    // 64 KB

    hipLaunchKernelGGL(asd_k1, dim3(260), dim3(1024), 0, stream,
                       slots, Wproj, bproj, s2, Wpack);
    hipLaunchKernelGGL(asd_k2, dim3(512), dim3(256), 0, stream,
                       feat, s2, Wpack, whead, bhead, out);
}